// Round 16
// baseline (285.698 us; speedup 1.0000x reference)
//
#include <hip/hip_runtime.h>
#include <hip/hip_bf16.h>

#define B_ 8
#define D_ 40
#define T_ 192
#define G_ 256
#define U_ 768   // 3*UNITS
#define H_ 256   // UNITS

// Keep a value opaque/live in a VGPR (defeats in-loop reload; R10: FETCH halved)
#define PINV(x) asm volatile("" : "+v"(x))

__device__ inline float sigmoidf_(float x){
  return 1.0f/(1.0f+__expf(-x));
}
__device__ inline float tanhf_(float x){
  float ax = fabsf(x);
  float e = __expf(-2.0f*ax);
  float t = (1.0f-e)/(1.0f+e);
  return copysignf(t, x);
}
__device__ inline int sdot4(int a, int b, int c){
#if __has_builtin(__builtin_amdgcn_sdot4)
  return __builtin_amdgcn_sdot4(a, b, c, false);
#else
  int r = c;
  #pragma unroll
  for (int i=0;i<4;i++){
    int ai = (a << (24-8*i)) >> 24;
    int bi = (b << (24-8*i)) >> 24;
    r += ai*bi;
  }
  return r;
#endif
}
__device__ inline int pack4(int q0,int q1,int q2,int q3){
  return (q0&255) | ((q1&255)<<8) | ((q2&255)<<16) | ((q3&255)<<24);
}

// ---------------- Kernel 1: single-channel interp + per-(b,d) mean ----------
// (mask branch is block-uniform -> scalar-branch skip already compacts)
__global__ __launch_bounds__(256) void k_interp(
    const float* __restrict__ times, const float* __restrict__ values,
    const float* __restrict__ meas, const float* __restrict__ grid,
    const float* __restrict__ ksic,
    float* __restrict__ y, float* __restrict__ w, float* __restrict__ ytr,
    float* __restrict__ mean){
  int bd = blockIdx.x;            // b*D_+d
  int b = bd / D_, d = bd % D_;
  int g = threadIdx.x;
  __shared__ float tt[T_], vv[T_], mm[T_];
  __shared__ float red[256];
  if (g < T_){
    tt[g] = times[bd*T_+g];
    vv[g] = values[bd*T_+g];
    mm[g] = meas[bd*T_+g];
  }
  __syncthreads();
  float alpha = log1pf(__expf(ksic[d]));   // softplus
  float tg = grid[b*G_+g];
  float nmin = 3.4e38f;
  for (int t=0;t<T_;t++){
    if (mm[t] > 0.0f){
      float dd = tt[t]-tg;
      nmin = fminf(nmin, dd*dd);
    }
  }
  float s1=0.f, sv1=0.f, s10=0.f, sv10=0.f;
  for (int t=0;t<T_;t++){
    if (mm[t] > 0.0f){
      float dd = tt[t]-tg;
      float n = dd*dd - nmin;               // >= 0
      float e1  = __expf(-alpha*n);
      float e10 = __expf(-10.0f*alpha*n);
      s1 += e1;  sv1 += e1*vv[t];
      s10 += e10; sv10 += e10*vv[t];
    }
  }
  float yv = sv1/s1;
  float wv = -alpha*nmin + __logf(s1);
  y[bd*G_+g]   = yv;
  w[bd*G_+g]   = wv;
  ytr[bd*G_+g] = sv10/s10;
  red[g] = yv;
  __syncthreads();
  for (int s=128;s>0;s>>=1){
    if (g<s) red[g]+=red[g+s];
    __syncthreads();
  }
  if (g==0) mean[bd] = red[0]*(1.0f/(float)G_);
}

// ------- Kernel 2: cross-channel interp + feats + x_proj (8 g per block) ----
// Wx is the dominant residual traffic. R13's 4-g amortization: 754->188MB,
// -11us. This round: 8 g per block (256 blocks) -> 94MB. Each Wx element
// loaded once feeds 8 accumulators (statically-indexed registers).
__global__ __launch_bounds__(256) void k_cross(
    const float* __restrict__ y, const float* __restrict__ w,
    const float* __restrict__ ytr, const float* __restrict__ mean,
    const float* __restrict__ crossW, const float* __restrict__ Wx,
    const float* __restrict__ gru_b, const int* __restrict__ lens,
    float* __restrict__ xproj){
  int blk = blockIdx.x;             // b*32 + gq
  int b = blk >> 5, gq = blk & 31;
  int g0 = gq*8;
  if (g0 >= lens[b]) return;        // whole octet unused (frozen in k_gru)
  __shared__ float wd[8][D_], yd[8][D_], ytrd[8][D_], md[D_];
  __shared__ float cc8[8][D_], feats[8][3*D_];
  __shared__ float wstat[8][2];
  int tid = threadIdx.x;
  // load 8x40 slots (320 > 256 threads -> strided loop)
  for (int idx = tid; idx < 8*D_; idx += 256){
    int gg = idx / D_, d = idx % D_;
    int src = (b*D_+d)*G_ + g0 + gg;
    wd[gg][d]=w[src]; yd[gg][d]=y[src]; ytrd[gg][d]=ytr[src];
  }
  if (tid < D_) md[tid] = mean[b*D_+tid];
  __syncthreads();
  if (tid < 8){                     // 8 parallel softmax scans
    float mx=-3.4e38f;
    for (int d2=0;d2<D_;d2++) mx = fmaxf(mx, wd[tid][d2]);
    float s=0.f;
    for (int d2=0;d2<D_;d2++) s += __expf(wd[tid][d2]-mx);
    wstat[tid][0]=mx; wstat[tid][1]=1.0f/s;
  }
  __syncthreads();
  for (int idx = tid; idx < 8*D_; idx += 256){
    int gg = idx / D_, d = idx % D_;
    float sw = __expf(wd[gg][d]-wstat[gg][0])*wstat[gg][1];
    cc8[gg][d] = sw*(yd[gg][d]-md[d]);
  }
  __syncthreads();
  for (int idx = tid; idx < 8*D_; idx += 256){
    int gg = idx / D_, d = idx % D_;
    float acc=0.f;
    for (int d2=0;d2<D_;d2++) acc += cc8[gg][d2]*crossW[d2*D_+d];
    float rep = acc + md[d];
    feats[gg][d]       = rep;                    // rep1
    feats[gg][D_+d]    = __expf(wd[gg][d]);      // intensity
    feats[gg][2*D_+d]  = ytrd[gg][d]-rep;        // y_trans - rep1
  }
  __syncthreads();
  for (int jj=0;jj<3;jj++){
    int j = tid + jj*256;
    float bi = gru_b[j];
    float a0=bi,a1=bi,a2=bi,a3=bi,a4=bi,a5=bi,a6=bi,a7=bi;
    #pragma unroll 4
    for (int i=0;i<3*D_;i++){
      float wv = Wx[i*U_+j];        // one load feeds 8 g's
      a0 += feats[0][i]*wv;  a1 += feats[1][i]*wv;
      a2 += feats[2][i]*wv;  a3 += feats[3][i]*wv;
      a4 += feats[4][i]*wv;  a5 += feats[5][i]*wv;
      a6 += feats[6][i]*wv;  a7 += feats[7][i]*wv;
    }
    size_t base = ((size_t)(b*G_+g0))*U_ + j;
    xproj[base]      = a0;          // g >= len slots written, never read
    xproj[base+U_]   = a1;
    xproj[base+2*U_] = a2;
    xproj[base+3*U_] = a3;
    xproj[base+4*U_] = a4;
    xproj[base+5*U_] = a5;
    xproj[base+6*U_] = a6;
    xproj[base+7*U_] = a7;
  }
}

// ---------------- Kernel 3: demo MLP -> h0 ----------------------------------
__global__ __launch_bounds__(256) void k_demo(
    const float* __restrict__ demo, const float* __restrict__ W1,
    const float* __restrict__ b1, const float* __restrict__ W2,
    const float* __restrict__ b2, float* __restrict__ h0){
  __shared__ float dl[B_*16];
  __shared__ float hid[B_*H_];
  int u = threadIdx.x;
  if (u < B_*16) dl[u] = demo[u];
  __syncthreads();
  float acc[B_];
  #pragma unroll
  for (int b=0;b<B_;b++) acc[b]=b1[u];
  for (int i=0;i<16;i++){
    float w1 = W1[i*H_+u];
    #pragma unroll
    for (int b=0;b<B_;b++) acc[b] += dl[b*16+i]*w1;
  }
  #pragma unroll
  for (int b=0;b<B_;b++) hid[b*H_+u] = fmaxf(acc[b],0.f);
  __syncthreads();
  #pragma unroll
  for (int b=0;b<B_;b++) acc[b]=b2[u];
  for (int k=0;k<H_;k++){
    float w2 = W2[k*H_+u];
    #pragma unroll
    for (int b=0;b<B_;b++) acc[b] += hid[b*H_+k]*w2;
  }
  #pragma unroll
  for (int b=0;b<B_;b++) h0[b*H_+u]=acc[b];
}

// ---------------- Kernel 3b: quantize Wh -> int8 packed (parallel) ----------
__global__ __launch_bounds__(256) void k_quant(
    const float* __restrict__ Wh, int* __restrict__ wsq,
    float* __restrict__ wmaxs){
  int c0 = blockIdx.x*64;
  int rg = threadIdx.x >> 6;       // 0..3
  int cc = threadIdx.x & 63;
  int col = c0 + cc;
  float v[64];
  float mx = 0.f;
  #pragma unroll
  for (int r=0;r<64;r++){
    v[r] = Wh[(size_t)(rg*64+r)*U_ + col];
    mx = fmaxf(mx, fabsf(v[r]));
  }
  __shared__ float cm[4][64];
  cm[rg][cc] = mx;
  __syncthreads();
  float m = fmaxf(fmaxf(cm[0][cc],cm[1][cc]), fmaxf(cm[2][cc],cm[3][cc]));
  float iw = (m>0.f)? 127.0f/m : 0.f;
  if (rg==0) wmaxs[col] = m;
  #pragma unroll
  for (int k=0;k<16;k++){
    int q0=(int)rintf(v[4*k+0]*iw), q1=(int)rintf(v[4*k+1]*iw),
        q2=(int)rintf(v[4*k+2]*iw), q3=(int)rintf(v[4*k+3]*iw);
    wsq[(size_t)(rg*16+k)*U_ + col] = pack4(q0,q1,q2,q3);
  }
}

// ---------------- Kernel 4: masked GRU, int8 (R10/R13 body - converged) -----
// Plateau proven across 7 structural variants (R8-R15: 844-906 ns/step at
// 1/2/3 waves per SIMD, gate-split, batch-split, MFMA): step time is a
// serial-chain latency floor (barrier + LDS round-trip + dot + transcendental
// chain), invariant to issue-side restructuring. This is the best variant.
__global__ __attribute__((amdgpu_flat_work_group_size(256,256), amdgpu_waves_per_eu(1,1)))
void k_gru(
    const int* __restrict__ wsq, const float* __restrict__ wmaxs,
    const float* __restrict__ gru_b,
    const float* __restrict__ xproj, const float* __restrict__ h0,
    const int* __restrict__ lens, const float* __restrict__ outW,
    const float* __restrict__ outb, float* __restrict__ out){
  int b = blockIdx.x;
  int j = threadIdx.x;

  __shared__ __align__(16) int hq[2][64];   // packed i8 h, double-buffered
  __shared__ float red[H_];
  __shared__ float shs[2];                  // [0]=inv_sh, [1]=s_h

  // ---- h0 + abs-max (fixed h scale; |h_new| <= max(|h_old|,1)) ----
  float hj = h0[b*H_+j];
  red[j] = fabsf(hj);
  __syncthreads();
  for (int st=128; st>0; st>>=1){
    if (j < st) red[j] = fmaxf(red[j], red[j+st]);
    __syncthreads();
  }
  if (j==0){
    float bound = fmaxf(red[0], 1.0f);
    shs[0] = 127.0f/bound;
    shs[1] = bound/127.0f;
  }
  __syncthreads();
  float inv_sh = shs[0];
  float s_h    = shs[1];

  // per-column dequant factors
  float cm0 = wmaxs[j], cm1 = wmaxs[H_+j], cm2 = wmaxs[2*H_+j];
  float fz = (cm0*(1.0f/127.0f))*s_h;
  float fr = (cm1*(1.0f/127.0f))*s_h;
  float fh = (cm2*(1.0f/127.0f))*s_h;
  float brz = gru_b[U_+j], brr = gru_b[U_+H_+j], brh = gru_b[U_+2*H_+j];

  // ---- load pre-packed weights (coalesced across j) and PIN in VGPRs ----
  int wqz[64], wqr[64], wqh[64];
  #pragma unroll
  for (int k=0;k<64;k++){ wqz[k] = wsq[(size_t)k*U_ + j];        PINV(wqz[k]); }
  #pragma unroll
  for (int k=0;k<64;k++){ wqr[k] = wsq[(size_t)k*U_ + H_ + j];   PINV(wqr[k]); }
  #pragma unroll
  for (int k=0;k<64;k++){ wqh[k] = wsq[(size_t)k*U_ + 2*H_ + j]; PINV(wqh[k]); }

  {
    float qf = fmaxf(-127.f, fminf(127.f, rintf(hj*inv_sh)));
    ((signed char*)hq[0])[j] = (signed char)(int)qf;
  }
  int len = lens[b];
  const float* xbase = xproj + (size_t)b*G_*U_;
  float xpz = xbase[j], xpr = xbase[H_+j], xph = xbase[2*H_+j];
  __syncthreads();

  for (int g=0; g<len; g++){
    // prefetch next step's x (consumed next iteration; hides HBM latency)
    float nxz=0.f, nxr=0.f, nxh=0.f;
    if (g+1 < len){
      const float* xn = xbase + (size_t)(g+1)*U_;
      nxz = xn[j]; nxr = xn[H_+j]; nxh = xn[2*H_+j];
    }
    const int4* hc = (const int4*)hq[g&1];
    int az=0, ar=0, ah=0;
    #pragma unroll
    for (int c=0;c<16;c++){
      int4 hv = hc[c];                              // broadcast ds_read_b128
      az=sdot4(hv.x,wqz[4*c+0],az); ar=sdot4(hv.x,wqr[4*c+0],ar); ah=sdot4(hv.x,wqh[4*c+0],ah);
      az=sdot4(hv.y,wqz[4*c+1],az); ar=sdot4(hv.y,wqr[4*c+1],ar); ah=sdot4(hv.y,wqh[4*c+1],ah);
      az=sdot4(hv.z,wqz[4*c+2],az); ar=sdot4(hv.z,wqr[4*c+2],ar); ah=sdot4(hv.z,wqh[4*c+2],ah);
      az=sdot4(hv.w,wqz[4*c+3],az); ar=sdot4(hv.w,wqr[4*c+3],ar); ah=sdot4(hv.w,wqh[4*c+3],ah);
    }
    float z    = sigmoidf_(xpz + brz + fz*(float)az);
    float r    = sigmoidf_(xpr + brr + fr*(float)ar);
    float cand = tanhf_(xph + r*(brh + fh*(float)ah));
    hj = z*hj + (1.0f-z)*cand;
    float qf = fmaxf(-127.f, fminf(127.f, rintf(hj*inv_sh)));
    ((signed char*)hq[(g+1)&1])[j] = (signed char)(int)qf;
    __syncthreads();                 // single barrier per step
    xpz = nxz; xpr = nxr; xph = nxh;
  }

  // out = sigmoid(h . outW + outb)
  red[j] = hj*outW[j];
  __syncthreads();
  for (int st=128;st>0;st>>=1){
    if (j<st) red[j]+=red[j+st];
    __syncthreads();
  }
  if (j==0) out[b] = sigmoidf_(red[0]+outb[0]);
}

extern "C" void kernel_launch(void* const* d_in, const int* in_sizes, int n_in,
                              void* d_out, int out_size, void* d_ws, size_t ws_size,
                              hipStream_t stream) {
  const float* demo   = (const float*)d_in[0];
  const float* times  = (const float*)d_in[1];
  const float* values = (const float*)d_in[2];
  const float* meas   = (const float*)d_in[3];
  const float* grid   = (const float*)d_in[4];
  const float* ksic   = (const float*)d_in[5];
  const float* crossW = (const float*)d_in[6];
  const float* dW1    = (const float*)d_in[7];
  const float* db1    = (const float*)d_in[8];
  const float* dW2    = (const float*)d_in[9];
  const float* db2    = (const float*)d_in[10];
  const float* gWx    = (const float*)d_in[11];
  const float* gWh    = (const float*)d_in[12];
  const float* gb     = (const float*)d_in[13];
  const float* outW   = (const float*)d_in[14];
  const float* outb   = (const float*)d_in[15];
  const int*   lens   = (const int*)d_in[16];
  float* out = (float*)d_out;

  float* ws   = (float*)d_ws;
  float* y    = ws;                        // B*D*G
  float* w    = y    + B_*D_*G_;
  float* ytr  = w    + B_*D_*G_;
  float* mean = ytr  + B_*D_*G_;
  float* h0   = mean + B_*D_;
  float* xprj = h0   + B_*H_;              // B*G*768
  int*   wsq  = (int*)(xprj + (size_t)B_*G_*U_);   // 64*768 dwords (192KB)
  float* wmx  = (float*)(wsq + 64*U_);             // 768 floats

  k_interp<<<B_*D_, 256, 0, stream>>>(times, values, meas, grid, ksic, y, w, ytr, mean);
  k_quant <<<12,    256, 0, stream>>>(gWh, wsq, wmx);
  k_demo  <<<1,     256, 0, stream>>>(demo, dW1, db1, dW2, db2, h0);
  k_cross <<<B_*32, 256, 0, stream>>>(y, w, ytr, mean, crossW, gWx, gb, lens, xprj);
  k_gru   <<<B_,    256, 0, stream>>>(wsq, wmx, gb, xprj, h0, lens, outW, outb, out);
}

// Round 17
// 284.112 us; speedup vs baseline: 1.0056x; 1.0056x over previous
//
#include <hip/hip_runtime.h>
#include <hip/hip_bf16.h>

#define B_ 8
#define D_ 40
#define T_ 192
#define G_ 256
#define U_ 768   // 3*UNITS
#define H_ 256   // UNITS

// Keep a value opaque/live in a VGPR (defeats in-loop reload; R10: FETCH halved)
#define PINV(x) asm volatile("" : "+v"(x))

__device__ inline float sigmoidf_(float x){
  return 1.0f/(1.0f+__expf(-x));
}
__device__ inline float tanhf_(float x){
  float ax = fabsf(x);
  float e = __expf(-2.0f*ax);
  float t = (1.0f-e)/(1.0f+e);
  return copysignf(t, x);
}
__device__ inline int sdot4(int a, int b, int c){
#if __has_builtin(__builtin_amdgcn_sdot4)
  return __builtin_amdgcn_sdot4(a, b, c, false);
#else
  int r = c;
  #pragma unroll
  for (int i=0;i<4;i++){
    int ai = (a << (24-8*i)) >> 24;
    int bi = (b << (24-8*i)) >> 24;
    r += ai*bi;
  }
  return r;
#endif
}
__device__ inline int pack4(int q0,int q1,int q2,int q3){
  return (q0&255) | ((q1&255)<<8) | ((q2&255)<<16) | ((q3&255)<<24);
}

// ---------------- Kernel 1: single-channel interp + per-(b,d) mean ----------
__global__ __launch_bounds__(256) void k_interp(
    const float* __restrict__ times, const float* __restrict__ values,
    const float* __restrict__ meas, const float* __restrict__ grid,
    const float* __restrict__ ksic,
    float* __restrict__ y, float* __restrict__ w, float* __restrict__ ytr,
    float* __restrict__ mean){
  int bd = blockIdx.x;            // b*D_+d
  int b = bd / D_, d = bd % D_;
  int g = threadIdx.x;
  __shared__ float tt[T_], vv[T_], mm[T_];
  __shared__ float red[256];
  if (g < T_){
    tt[g] = times[bd*T_+g];
    vv[g] = values[bd*T_+g];
    mm[g] = meas[bd*T_+g];
  }
  __syncthreads();
  float alpha = log1pf(__expf(ksic[d]));   // softplus
  float tg = grid[b*G_+g];
  float nmin = 3.4e38f;
  for (int t=0;t<T_;t++){
    if (mm[t] > 0.0f){
      float dd = tt[t]-tg;
      nmin = fminf(nmin, dd*dd);
    }
  }
  float s1=0.f, sv1=0.f, s10=0.f, sv10=0.f;
  for (int t=0;t<T_;t++){
    if (mm[t] > 0.0f){
      float dd = tt[t]-tg;
      float n = dd*dd - nmin;               // >= 0
      float e1  = __expf(-alpha*n);
      float e10 = __expf(-10.0f*alpha*n);
      s1 += e1;  sv1 += e1*vv[t];
      s10 += e10; sv10 += e10*vv[t];
    }
  }
  float yv = sv1/s1;
  float wv = -alpha*nmin + __logf(s1);
  y[bd*G_+g]   = yv;
  w[bd*G_+g]   = wv;
  ytr[bd*G_+g] = sv10/s10;
  red[g] = yv;
  __syncthreads();
  for (int s=128;s>0;s>>=1){
    if (g<s) red[g]+=red[g+s];
    __syncthreads();
  }
  if (g==0) mean[bd] = red[0]*(1.0f/(float)G_);
}

// ------- Kernel 2: cross-channel interp + feats + x_proj (4 g per block) ----
// (R13 version — best measured; 8-g variant was neutral, reverted)
__global__ __launch_bounds__(256) void k_cross(
    const float* __restrict__ y, const float* __restrict__ w,
    const float* __restrict__ ytr, const float* __restrict__ mean,
    const float* __restrict__ crossW, const float* __restrict__ Wx,
    const float* __restrict__ gru_b, const int* __restrict__ lens,
    float* __restrict__ xproj){
  int blk = blockIdx.x;             // b*64 + gq
  int b = blk >> 6, gq = blk & 63;
  int g0 = gq*4;
  if (g0 >= lens[b]) return;        // whole quad unused
  __shared__ float wd[4][D_], yd[4][D_], ytrd[4][D_], md[D_];
  __shared__ float cc4[4][D_], feats[4][3*D_];
  __shared__ float wstat[4][2];
  int tid = threadIdx.x;
  int gg = tid / D_;
  int d  = tid % D_;
  if (tid < 4*D_){
    int idx = (b*D_+d)*G_ + g0 + gg;
    wd[gg][d]=w[idx]; yd[gg][d]=y[idx]; ytrd[gg][d]=ytr[idx];
  }
  if (tid < D_) md[tid] = mean[b*D_+tid];
  __syncthreads();
  if (tid < 4){
    float mx=-3.4e38f;
    for (int d2=0;d2<D_;d2++) mx = fmaxf(mx, wd[tid][d2]);
    float s=0.f;
    for (int d2=0;d2<D_;d2++) s += __expf(wd[tid][d2]-mx);
    wstat[tid][0]=mx; wstat[tid][1]=1.0f/s;
  }
  __syncthreads();
  if (tid < 4*D_){
    float sw = __expf(wd[gg][d]-wstat[gg][0])*wstat[gg][1];
    cc4[gg][d] = sw*(yd[gg][d]-md[d]);
  }
  __syncthreads();
  if (tid < 4*D_){
    float acc=0.f;
    for (int d2=0;d2<D_;d2++) acc += cc4[gg][d2]*crossW[d2*D_+d];
    float rep = acc + md[d];
    feats[gg][d]       = rep;
    feats[gg][D_+d]    = __expf(wd[gg][d]);
    feats[gg][2*D_+d]  = ytrd[gg][d]-rep;
  }
  __syncthreads();
  for (int jj=0;jj<3;jj++){
    int j = tid + jj*256;
    float bi = gru_b[j];
    float a0=bi, a1=bi, a2=bi, a3=bi;
    #pragma unroll 4
    for (int i=0;i<3*D_;i++){
      float wv = Wx[i*U_+j];        // one load feeds 4 g's
      a0 += feats[0][i]*wv;
      a1 += feats[1][i]*wv;
      a2 += feats[2][i]*wv;
      a3 += feats[3][i]*wv;
    }
    size_t base = ((size_t)(b*G_+g0))*U_ + j;
    xproj[base]       = a0;
    xproj[base+U_]    = a1;
    xproj[base+2*U_]  = a2;
    xproj[base+3*U_]  = a3;
  }
}

// ---------------- Kernel 3: demo MLP -> h0 ----------------------------------
__global__ __launch_bounds__(256) void k_demo(
    const float* __restrict__ demo, const float* __restrict__ W1,
    const float* __restrict__ b1, const float* __restrict__ W2,
    const float* __restrict__ b2, float* __restrict__ h0){
  __shared__ float dl[B_*16];
  __shared__ float hid[B_*H_];
  int u = threadIdx.x;
  if (u < B_*16) dl[u] = demo[u];
  __syncthreads();
  float acc[B_];
  #pragma unroll
  for (int b=0;b<B_;b++) acc[b]=b1[u];
  for (int i=0;i<16;i++){
    float w1 = W1[i*H_+u];
    #pragma unroll
    for (int b=0;b<B_;b++) acc[b] += dl[b*16+i]*w1;
  }
  #pragma unroll
  for (int b=0;b<B_;b++) hid[b*H_+u] = fmaxf(acc[b],0.f);
  __syncthreads();
  #pragma unroll
  for (int b=0;b<B_;b++) acc[b]=b2[u];
  for (int k=0;k<H_;k++){
    float w2 = W2[k*H_+u];
    #pragma unroll
    for (int b=0;b<B_;b++) acc[b] += hid[b*H_+k]*w2;
  }
  #pragma unroll
  for (int b=0;b<B_;b++) h0[b*H_+u]=acc[b];
}

// ---------------- Kernel 3b: quantize Wh -> int8 packed (parallel) ----------
__global__ __launch_bounds__(256) void k_quant(
    const float* __restrict__ Wh, int* __restrict__ wsq,
    float* __restrict__ wmaxs){
  int c0 = blockIdx.x*64;
  int rg = threadIdx.x >> 6;       // 0..3
  int cc = threadIdx.x & 63;
  int col = c0 + cc;
  float v[64];
  float mx = 0.f;
  #pragma unroll
  for (int r=0;r<64;r++){
    v[r] = Wh[(size_t)(rg*64+r)*U_ + col];
    mx = fmaxf(mx, fabsf(v[r]));
  }
  __shared__ float cm[4][64];
  cm[rg][cc] = mx;
  __syncthreads();
  float m = fmaxf(fmaxf(cm[0][cc],cm[1][cc]), fmaxf(cm[2][cc],cm[3][cc]));
  float iw = (m>0.f)? 127.0f/m : 0.f;
  if (rg==0) wmaxs[col] = m;
  #pragma unroll
  for (int k=0;k<16;k++){
    int q0=(int)rintf(v[4*k+0]*iw), q1=(int)rintf(v[4*k+1]*iw),
        q2=(int)rintf(v[4*k+2]*iw), q3=(int)rintf(v[4*k+3]*iw);
    wsq[(size_t)(rg*16+k)*U_ + col] = pack4(q0,q1,q2,q3);
  }
}

// ---------------- Kernel 4: masked GRU, int8, raw-barrier step loop ---------
// R10/R13 body + ONE change: the in-loop __syncthreads() is replaced by
//   s_waitcnt lgkmcnt(0); s_barrier
// __syncthreads emits s_waitcnt vmcnt(0) before s_barrier (guide §5, m97 asm),
// which DRAINS the next-step xproj prefetch every step — the 1-deep prefetch
// never actually spanned a step boundary. Raw barrier (m201/m218-proven
// pattern) keeps the global loads in flight across the barrier; only LDS
// (lgkmcnt) must drain for the h-exchange. Cross-step buffer safety: step g+1
// writes hq[g&1] only after its own reads of hq[(g+1)&1]; reads of hq[g&1]
// in step g are drained by the lgkmcnt(0) before the end-of-g barrier.
__global__ __attribute__((amdgpu_flat_work_group_size(256,256), amdgpu_waves_per_eu(1,1)))
void k_gru(
    const int* __restrict__ wsq, const float* __restrict__ wmaxs,
    const float* __restrict__ gru_b,
    const float* __restrict__ xproj, const float* __restrict__ h0,
    const int* __restrict__ lens, const float* __restrict__ outW,
    const float* __restrict__ outb, float* __restrict__ out){
  int b = blockIdx.x;
  int j = threadIdx.x;

  __shared__ __align__(16) int hq[2][64];   // packed i8 h, double-buffered
  __shared__ float red[H_];
  __shared__ float shs[2];                  // [0]=inv_sh, [1]=s_h

  // ---- h0 + abs-max (fixed h scale; |h_new| <= max(|h_old|,1)) ----
  float hj = h0[b*H_+j];
  red[j] = fabsf(hj);
  __syncthreads();
  for (int st=128; st>0; st>>=1){
    if (j < st) red[j] = fmaxf(red[j], red[j+st]);
    __syncthreads();
  }
  if (j==0){
    float bound = fmaxf(red[0], 1.0f);
    shs[0] = 127.0f/bound;
    shs[1] = bound/127.0f;
  }
  __syncthreads();
  float inv_sh = shs[0];
  float s_h    = shs[1];

  // per-column dequant factors
  float cm0 = wmaxs[j], cm1 = wmaxs[H_+j], cm2 = wmaxs[2*H_+j];
  float fz = (cm0*(1.0f/127.0f))*s_h;
  float fr = (cm1*(1.0f/127.0f))*s_h;
  float fh = (cm2*(1.0f/127.0f))*s_h;
  float brz = gru_b[U_+j], brr = gru_b[U_+H_+j], brh = gru_b[U_+2*H_+j];

  // ---- load pre-packed weights (coalesced across j) and PIN in VGPRs ----
  int wqz[64], wqr[64], wqh[64];
  #pragma unroll
  for (int k=0;k<64;k++){ wqz[k] = wsq[(size_t)k*U_ + j];        PINV(wqz[k]); }
  #pragma unroll
  for (int k=0;k<64;k++){ wqr[k] = wsq[(size_t)k*U_ + H_ + j];   PINV(wqr[k]); }
  #pragma unroll
  for (int k=0;k<64;k++){ wqh[k] = wsq[(size_t)k*U_ + 2*H_ + j]; PINV(wqh[k]); }

  {
    float qf = fmaxf(-127.f, fminf(127.f, rintf(hj*inv_sh)));
    ((signed char*)hq[0])[j] = (signed char)(int)qf;
  }
  int len = lens[b];
  const float* xbase = xproj + (size_t)b*G_*U_;
  float xpz = xbase[j], xpr = xbase[H_+j], xph = xbase[2*H_+j];
  __syncthreads();

  for (int g=0; g<len; g++){
    // prefetch next step's x; with the raw barrier these loads now genuinely
    // stay in flight across the step boundary (vmcnt not drained).
    float nxz=0.f, nxr=0.f, nxh=0.f;
    if (g+1 < len){
      const float* xn = xbase + (size_t)(g+1)*U_;
      nxz = xn[j]; nxr = xn[H_+j]; nxh = xn[2*H_+j];
    }
    const int4* hc = (const int4*)hq[g&1];
    int az=0, ar=0, ah=0;
    #pragma unroll
    for (int c=0;c<16;c++){
      int4 hv = hc[c];                              // broadcast ds_read_b128
      az=sdot4(hv.x,wqz[4*c+0],az); ar=sdot4(hv.x,wqr[4*c+0],ar); ah=sdot4(hv.x,wqh[4*c+0],ah);
      az=sdot4(hv.y,wqz[4*c+1],az); ar=sdot4(hv.y,wqr[4*c+1],ar); ah=sdot4(hv.y,wqh[4*c+1],ah);
      az=sdot4(hv.z,wqz[4*c+2],az); ar=sdot4(hv.z,wqr[4*c+2],ar); ah=sdot4(hv.z,wqh[4*c+2],ah);
      az=sdot4(hv.w,wqz[4*c+3],az); ar=sdot4(hv.w,wqr[4*c+3],ar); ah=sdot4(hv.w,wqh[4*c+3],ah);
    }
    float z    = sigmoidf_(xpz + brz + fz*(float)az);
    float r    = sigmoidf_(xpr + brr + fr*(float)ar);
    float cand = tanhf_(xph + r*(brh + fh*(float)ah));
    hj = z*hj + (1.0f-z)*cand;
    float qf = fmaxf(-127.f, fminf(127.f, rintf(hj*inv_sh)));
    ((signed char*)hq[(g+1)&1])[j] = (signed char)(int)qf;
    // raw barrier: drain LDS only; global prefetch stays in flight
    asm volatile("s_waitcnt lgkmcnt(0)" ::: "memory");
    __builtin_amdgcn_s_barrier();
    xpz = nxz; xpr = nxr; xph = nxh;
  }

  // out = sigmoid(h . outW + outb)
  red[j] = hj*outW[j];
  __syncthreads();
  for (int st=128;st>0;st>>=1){
    if (j<st) red[j]+=red[j+st];
    __syncthreads();
  }
  if (j==0) out[b] = sigmoidf_(red[0]+outb[0]);
}

extern "C" void kernel_launch(void* const* d_in, const int* in_sizes, int n_in,
                              void* d_out, int out_size, void* d_ws, size_t ws_size,
                              hipStream_t stream) {
  const float* demo   = (const float*)d_in[0];
  const float* times  = (const float*)d_in[1];
  const float* values = (const float*)d_in[2];
  const float* meas   = (const float*)d_in[3];
  const float* grid   = (const float*)d_in[4];
  const float* ksic   = (const float*)d_in[5];
  const float* crossW = (const float*)d_in[6];
  const float* dW1    = (const float*)d_in[7];
  const float* db1    = (const float*)d_in[8];
  const float* dW2    = (const float*)d_in[9];
  const float* db2    = (const float*)d_in[10];
  const float* gWx    = (const float*)d_in[11];
  const float* gWh    = (const float*)d_in[12];
  const float* gb     = (const float*)d_in[13];
  const float* outW   = (const float*)d_in[14];
  const float* outb   = (const float*)d_in[15];
  const int*   lens   = (const int*)d_in[16];
  float* out = (float*)d_out;

  float* ws   = (float*)d_ws;
  float* y    = ws;                        // B*D*G
  float* w    = y    + B_*D_*G_;
  float* ytr  = w    + B_*D_*G_;
  float* mean = ytr  + B_*D_*G_;
  float* h0   = mean + B_*D_;
  float* xprj = h0   + B_*H_;              // B*G*768
  int*   wsq  = (int*)(xprj + (size_t)B_*G_*U_);   // 64*768 dwords (192KB)
  float* wmx  = (float*)(wsq + 64*U_);             // 768 floats

  k_interp<<<B_*D_, 256, 0, stream>>>(times, values, meas, grid, ksic, y, w, ytr, mean);
  k_quant <<<12,    256, 0, stream>>>(gWh, wsq, wmx);
  k_demo  <<<1,     256, 0, stream>>>(demo, dW1, db1, dW2, db2, h0);
  k_cross <<<B_*64, 256, 0, stream>>>(y, w, ytr, mean, crossW, gWx, gb, lens, xprj);
  k_gru   <<<B_,    256, 0, stream>>>(wsq, wmx, gb, xprj, h0, lens, outW, outb, out);
}